// Round 17
// baseline (310.915 us; speedup 1.0000x reference)
//
#include <hip/hip_runtime.h>
#include <stdint.h>

#define NN 10000
#define NE 50000
#define KTOT 4224   // 4096 (S) + 64 (hs/bias) + 64 (h/root)
#define SPLITK 11
#define KCH 384     // KTOT / SPLITK = 12 k-steps of 32 (3 LDS stages of 128)
#define NSTEP 12
#define KPAD2 136   // LDS row stride (halves) for a 128-col stage (272 B)
#define NEPI 625    // epi blocks = NN*16/256

typedef __attribute__((ext_vector_type(8))) _Float16 f16x8;
typedef __attribute__((ext_vector_type(4))) _Float16 f16x4;
typedef __attribute__((ext_vector_type(4))) float f32x4;

// fused: h = relu(x@lin0_w+b), u = relu(ea@nn1_w+b), deg[dst] histogram
__global__ void k_front(const float* __restrict__ x, const float* __restrict__ l0w,
                        const float* __restrict__ l0b, const float* __restrict__ ea,
                        const float* __restrict__ n1w, const float* __restrict__ n1b,
                        const int* __restrict__ ei, float* __restrict__ h,
                        float* __restrict__ u, int* __restrict__ deg) {
  int idx = blockIdx.x * blockDim.x + threadIdx.x;
  if (idx < NN * 64) {
    int n = idx >> 6, o = idx & 63;
    float acc = l0b[o];
    const float* xr = x + n * 20;
#pragma unroll
    for (int j = 0; j < 20; ++j) acc += xr[j] * l0w[j * 64 + o];
    h[idx] = acc > 0.f ? acc : 0.f;
  } else {
    int idx2 = idx - NN * 64;
    if (idx2 >= NE * 64) return;
    int e = idx2 >> 6, o = idx2 & 63;
    if (o == 0) atomicAdd(&deg[ei[NE + e]], 1);   // fused k_deg
    float acc = n1b[o];
    const float* er = ea + e * 5;
#pragma unroll
    for (int j = 0; j < 5; ++j) acc += er[j] * n1w[j * 64 + o];
    u[idx2] = acc > 0.f ? acc : 0.f;
  }
}

// exclusive scan of deg -> offs[0..NN], plus inv_denom = 1/max(deg,1)
__global__ void k_scan(const int* __restrict__ deg, int* __restrict__ offs,
                       float* __restrict__ inv_denom) {
  __shared__ int s[256];
  int t = threadIdx.x;
  int base = t * 40;
  int sum = 0;
  for (int j = 0; j < 40; ++j) {
    int n = base + j;
    sum += (n < NN) ? deg[n] : 0;
  }
  s[t] = sum;
  __syncthreads();
  for (int off = 1; off < 256; off <<= 1) {
    int v = (t >= off) ? s[t - off] : 0;
    __syncthreads();
    s[t] += v;
    __syncthreads();
  }
  int run = s[t] - sum;  // exclusive prefix for this thread's chunk
  for (int j = 0; j < 40; ++j) {
    int n = base + j;
    if (n < NN) {
      offs[n] = run;
      int d = deg[n];
      run += d;
      inv_denom[n] = 1.0f / (float)(d > 0 ? d : 1);
    }
  }
  if (t == 255) offs[NN] = s[255];
}

__global__ void k_csr(const int* __restrict__ ei, const int* __restrict__ offs,
                      int* __restrict__ cursor, int* __restrict__ csr_src,
                      int* __restrict__ csr_eid) {
  int e = blockIdx.x * blockDim.x + threadIdx.x;
  if (e >= NE) return;
  int d = ei[NE + e];
  int pos = offs[d] + atomicAdd(&cursor[d], 1);
  csr_src[pos] = ei[e];
  csr_eid[pos] = e;
}

// WF transposed [o][k] as fp16 hi/lo planes (W fp32-grade), o=0..63.
__global__ void k_wf(const float* __restrict__ w2, const float* __restrict__ b2,
                     const float* __restrict__ rootw, _Float16* __restrict__ wh,
                     _Float16* __restrict__ wl) {
  int idx = blockIdx.x * blockDim.x + threadIdx.x;
  if (idx >= 64 * KTOT) return;
  int o = idx / KTOT, c = idx - o * KTOT;
  float v;
  if (c < 4096) {
    v = w2[(c >> 6) * 4096 + (c & 63) * 64 + o];
  } else if (c < 4160) {
    v = b2[(c - 4096) * 64 + o];
  } else {
    v = rootw[(c - 4160) * 64 + o];
  }
  _Float16 hi = (_Float16)v;
  wh[idx] = hi;
  wl[idx] = (_Float16)(v - (float)hi);
}

// Per node: SV row = [ inv_d*S(k,i) (4096) | inv_d*hs (64) | h[n] (64) ] (fp16)
// One WAVE per node (2 nodes/block, 128 thr), lane = k. Edge QUADS per
// iteration; invalid slots masked by uk=0 (order-stable numerics).
__global__ void __launch_bounds__(128) k_scatter(
    const float* __restrict__ h, const float* __restrict__ u,
    const int* __restrict__ offs, const int* __restrict__ csr_src,
    const int* __restrict__ csr_eid, const float* __restrict__ inv_denom,
    _Float16* __restrict__ sv16, int chunk_start, int chunk_nodes) {
  __shared__ float hrow[2][4][64];
  int t = threadIdx.x;
  int wid = t >> 6, lane = t & 63;
  int n_local = blockIdx.x * 2 + wid;
  if (n_local >= chunk_nodes) return;
  int n = chunk_start + n_local;
  int beg = offs[n], end = offs[n + 1];
  int nE = end - beg;
  float invd = inv_denom[n];
  float acc[64];
#pragma unroll
  for (int i = 0; i < 64; ++i) acc[i] = 0.f;
  float hsacc = 0.f;
  float uc0 = 0.f, uc1 = 0.f, uc2 = 0.f, uc3 = 0.f;
  float hc0 = 0.f, hc1 = 0.f, hc2 = 0.f, hc3 = 0.f;
  if (0 < nE) { int e = csr_eid[beg + 0], s = csr_src[beg + 0];
    uc0 = u[(size_t)e * 64 + lane]; hc0 = h[(size_t)s * 64 + lane]; }
  if (1 < nE) { int e = csr_eid[beg + 1], s = csr_src[beg + 1];
    uc1 = u[(size_t)e * 64 + lane]; hc1 = h[(size_t)s * 64 + lane]; }
  if (2 < nE) { int e = csr_eid[beg + 2], s = csr_src[beg + 2];
    uc2 = u[(size_t)e * 64 + lane]; hc2 = h[(size_t)s * 64 + lane]; }
  if (3 < nE) { int e = csr_eid[beg + 3], s = csr_src[beg + 3];
    uc3 = u[(size_t)e * 64 + lane]; hc3 = h[(size_t)s * 64 + lane]; }
  for (int c = 0; c < nE; c += 4) {
    hrow[wid][0][lane] = hc0;
    hrow[wid][1][lane] = hc1;
    hrow[wid][2][lane] = hc2;
    hrow[wid][3][lane] = hc3;
    hsacc += hc0 + hc1 + hc2 + hc3;    // invalid slots are 0
    float uk0 = uc0, uk1 = uc1, uk2 = uc2, uk3 = uc3;
    // prefetch next quad (issue before FMA burst)
    uc0 = uc1 = uc2 = uc3 = 0.f;
    hc0 = hc1 = hc2 = hc3 = 0.f;
    if (c + 4 < nE) { int e = csr_eid[beg + c + 4], s = csr_src[beg + c + 4];
      uc0 = u[(size_t)e * 64 + lane]; hc0 = h[(size_t)s * 64 + lane]; }
    if (c + 5 < nE) { int e = csr_eid[beg + c + 5], s = csr_src[beg + c + 5];
      uc1 = u[(size_t)e * 64 + lane]; hc1 = h[(size_t)s * 64 + lane]; }
    if (c + 6 < nE) { int e = csr_eid[beg + c + 6], s = csr_src[beg + c + 6];
      uc2 = u[(size_t)e * 64 + lane]; hc2 = h[(size_t)s * 64 + lane]; }
    if (c + 7 < nE) { int e = csr_eid[beg + c + 7], s = csr_src[beg + c + 7];
      uc3 = u[(size_t)e * 64 + lane]; hc3 = h[(size_t)s * 64 + lane]; }
#pragma unroll
    for (int j = 0; j < 16; ++j) {
      float4 r0 = *(const float4*)&hrow[wid][0][j * 4];
      float4 r1 = *(const float4*)&hrow[wid][1][j * 4];
      float4 r2 = *(const float4*)&hrow[wid][2][j * 4];
      float4 r3 = *(const float4*)&hrow[wid][3][j * 4];
      acc[j * 4 + 0] += uk0 * r0.x + uk1 * r1.x + uk2 * r2.x + uk3 * r3.x;
      acc[j * 4 + 1] += uk0 * r0.y + uk1 * r1.y + uk2 * r2.y + uk3 * r3.y;
      acc[j * 4 + 2] += uk0 * r0.z + uk1 * r1.z + uk2 * r2.z + uk3 * r3.z;
      acc[j * 4 + 3] += uk0 * r0.w + uk1 * r1.w + uk2 * r2.w + uk3 * r3.w;
    }
  }
  size_t rowo = (size_t)n_local * KTOT + (size_t)lane * 64;
#pragma unroll
  for (int j = 0; j < 8; ++j) {
    f16x8 v;
#pragma unroll
    for (int q = 0; q < 8; ++q) v[q] = (_Float16)(acc[j * 8 + q] * invd);
    *(f16x8*)(sv16 + rowo + j * 8) = v;
  }
  size_t base = (size_t)n_local * KTOT;
  sv16[base + 4096 + lane] = (_Float16)(hsacc * invd);
  sv16[base + 4160 + lane] = (_Float16)(h[(size_t)n * 64 + lane]);
}

// Split-K MFMA GEMM, fp16 2-pass, B in LDS (3 stages of 128), 2-stripe.
// K-steps processed in PAIRS with 2-deep A register prefetch (named regs,
// rule #20). Stage boundaries (ks=0,4,8) land on pair tops. kpart fp16.
__global__ void __launch_bounds__(256) k_mfma(
    const _Float16* __restrict__ sv16, const _Float16* __restrict__ wh,
    const _Float16* __restrict__ wl, _Float16* __restrict__ part,
    int chunk_start, int chunk_nodes) {
  __shared__ _Float16 Bh_s[64 * KPAD2];
  __shared__ _Float16 Bl_s[64 * KPAD2];
  int t = threadIdx.x;
  int wid = t >> 6, lane = t & 63;
  int node0 = blockIdx.x * 128;
  int kc = blockIdx.y;
  int r16 = lane & 15, kg = lane >> 4;
  int row0 = node0 + wid * 16 + r16;         // stripe 0
  int row1 = row0 + 64;                      // stripe 1
  int rg0 = row0 < chunk_nodes ? row0 : (chunk_nodes - 1);
  int rg1 = row1 < chunk_nodes ? row1 : (chunk_nodes - 1);
  const _Float16* pa0 = sv16 + (size_t)rg0 * KTOT + kg * 8;
  const _Float16* pa1 = sv16 + (size_t)rg1 * KTOT + kg * 8;
  f32x4 p0 = {0.f, 0.f, 0.f, 0.f}, p1 = p0, p2 = p0, p3 = p0;   // stripe 0
  f32x4 q0 = p0, q1 = p0, q2 = p0, q3 = p0;                      // stripe 1
  const int kb0 = kc * KCH;
  // 2-deep prefetch: c* = step ks, d* = step ks+1
  f16x8 c0 = *(const f16x8*)(pa0 + kb0);
  f16x8 c1 = *(const f16x8*)(pa1 + kb0);
  f16x8 d0 = *(const f16x8*)(pa0 + kb0 + 32);
  f16x8 d1 = *(const f16x8*)(pa1 + kb0 + 32);
  const int lb = r16 * KPAD2 + kg * 8;   // lane's LDS base (o-row r16)
#pragma unroll 1
  for (int ks = 0; ks < NSTEP; ks += 2) {
    if ((ks & 3) == 0) {                // (re)stage B: 128 cols, both planes
      __syncthreads();                  // prior stage fully consumed
      int gb = kb0 + (ks >> 2) * 128;
#pragma unroll
      for (int j = 0; j < 4; ++j) {
        int c = j * 256 + t;            // 0..1023
        int o = c >> 4, kk = (c & 15) * 8;
        *(f16x8*)&Bh_s[o * KPAD2 + kk] = *(const f16x8*)&wh[(size_t)o * KTOT + gb + kk];
        *(f16x8*)&Bl_s[o * KPAD2 + kk] = *(const f16x8*)&wl[(size_t)o * KTOT + gb + kk];
      }
      __syncthreads();
    }
    // prefetch steps ks+2, ks+3 (clamped)
    int kp2 = kb0 + ((ks + 2 < NSTEP) ? (ks + 2) : (NSTEP - 1)) * 32;
    int kp3 = kb0 + ((ks + 3 < NSTEP) ? (ks + 3) : (NSTEP - 1)) * 32;
    f16x8 e0 = *(const f16x8*)(pa0 + kp2);
    f16x8 e1 = *(const f16x8*)(pa1 + kp2);
    f16x8 f0 = *(const f16x8*)(pa0 + kp3);
    f16x8 f1 = *(const f16x8*)(pa1 + kp3);
    // ---- step ks (A = c0,c1) ----
    {
      int lk = lb + (ks & 3) * 32;
      f16x8 bh0 = *(const f16x8*)&Bh_s[lk];
      f16x8 bh1 = *(const f16x8*)&Bh_s[lk + 16 * KPAD2];
      f16x8 bh2 = *(const f16x8*)&Bh_s[lk + 32 * KPAD2];
      f16x8 bh3 = *(const f16x8*)&Bh_s[lk + 48 * KPAD2];
      f16x8 bl0 = *(const f16x8*)&Bl_s[lk];
      f16x8 bl1 = *(const f16x8*)&Bl_s[lk + 16 * KPAD2];
      f16x8 bl2 = *(const f16x8*)&Bl_s[lk + 32 * KPAD2];
      f16x8 bl3 = *(const f16x8*)&Bl_s[lk + 48 * KPAD2];
      p0 = __builtin_amdgcn_mfma_f32_16x16x32_f16(c0, bh0, p0, 0, 0, 0);
      p1 = __builtin_amdgcn_mfma_f32_16x16x32_f16(c0, bh1, p1, 0, 0, 0);
      p2 = __builtin_amdgcn_mfma_f32_16x16x32_f16(c0, bh2, p2, 0, 0, 0);
      p3 = __builtin_amdgcn_mfma_f32_16x16x32_f16(c0, bh3, p3, 0, 0, 0);
      p0 = __builtin_amdgcn_mfma_f32_16x16x32_f16(c0, bl0, p0, 0, 0, 0);
      p1 = __builtin_amdgcn_mfma_f32_16x16x32_f16(c0, bl1, p1, 0, 0, 0);
      p2 = __builtin_amdgcn_mfma_f32_16x16x32_f16(c0, bl2, p2, 0, 0, 0);
      p3 = __builtin_amdgcn_mfma_f32_16x16x32_f16(c0, bl3, p3, 0, 0, 0);
      q0 = __builtin_amdgcn_mfma_f32_16x16x32_f16(c1, bh0, q0, 0, 0, 0);
      q1 = __builtin_amdgcn_mfma_f32_16x16x32_f16(c1, bh1, q1, 0, 0, 0);
      q2 = __builtin_amdgcn_mfma_f32_16x16x32_f16(c1, bh2, q2, 0, 0, 0);
      q3 = __builtin_amdgcn_mfma_f32_16x16x32_f16(c1, bh3, q3, 0, 0, 0);
      q0 = __builtin_amdgcn_mfma_f32_16x16x32_f16(c1, bl0, q0, 0, 0, 0);
      q1 = __builtin_amdgcn_mfma_f32_16x16x32_f16(c1, bl1, q1, 0, 0, 0);
      q2 = __builtin_amdgcn_mfma_f32_16x16x32_f16(c1, bl2, q2, 0, 0, 0);
      q3 = __builtin_amdgcn_mfma_f32_16x16x32_f16(c1, bl3, q3, 0, 0, 0);
    }
    // ---- step ks+1 (A = d0,d1) ----
    {
      int lk = lb + ((ks + 1) & 3) * 32;
      f16x8 bh0 = *(const f16x8*)&Bh_s[lk];
      f16x8 bh1 = *(const f16x8*)&Bh_s[lk + 16 * KPAD2];
      f16x8 bh2 = *(const f16x8*)&Bh_s[lk + 32 * KPAD2];
      f16x8 bh3 = *(const f16x8*)&Bh_s[lk + 48 * KPAD2];
      f16x8 bl0 = *(const f16x8*)&Bl_s[lk];
      f16x8 bl1 = *(const f16x8*)&Bl_s[lk + 16 * KPAD2];
      f16x8 bl2 = *(const f16x8*)&Bl_s[lk + 32 * KPAD2];
      f16x8 bl3 = *(const f16x8*)&Bl_s[lk + 48 * KPAD2];
      p0 = __builtin_amdgcn_mfma_f32_16x16x32_f16(d0, bh0, p0, 0, 0, 0);
      p1 = __builtin_amdgcn_mfma_f32_16x16x32_f16(d0, bh1, p1, 0, 0, 0);
      p2 = __builtin_amdgcn_mfma_f32_16x16x32_f16(d0, bh2, p2, 0, 0, 0);
      p3 = __builtin_amdgcn_mfma_f32_16x16x32_f16(d0, bh3, p3, 0, 0, 0);
      p0 = __builtin_amdgcn_mfma_f32_16x16x32_f16(d0, bl0, p0, 0, 0, 0);
      p1 = __builtin_amdgcn_mfma_f32_16x16x32_f16(d0, bl1, p1, 0, 0, 0);
      p2 = __builtin_amdgcn_mfma_f32_16x16x32_f16(d0, bl2, p2, 0, 0, 0);
      p3 = __builtin_amdgcn_mfma_f32_16x16x32_f16(d0, bl3, p3, 0, 0, 0);
      q0 = __builtin_amdgcn_mfma_f32_16x16x32_f16(d1, bh0, q0, 0, 0, 0);
      q1 = __builtin_amdgcn_mfma_f32_16x16x32_f16(d1, bh1, q1, 0, 0, 0);
      q2 = __builtin_amdgcn_mfma_f32_16x16x32_f16(d1, bh2, q2, 0, 0, 0);
      q3 = __builtin_amdgcn_mfma_f32_16x16x32_f16(d1, bh3, q3, 0, 0, 0);
      q0 = __builtin_amdgcn_mfma_f32_16x16x32_f16(d1, bl0, q0, 0, 0, 0);
      q1 = __builtin_amdgcn_mfma_f32_16x16x32_f16(d1, bl1, q1, 0, 0, 0);
      q2 = __builtin_amdgcn_mfma_f32_16x16x32_f16(d1, bl2, q2, 0, 0, 0);
      q3 = __builtin_amdgcn_mfma_f32_16x16x32_f16(d1, bl3, q3, 0, 0, 0);
    }
    c0 = e0; c1 = e1; d0 = f0; d1 = f1;
  }
  // C/D layout: col = lane&15, row = (lane>>4)*4 + reg  [m89]
  _Float16* pp0 = part + (size_t)kc * NN * 64 +
                  (size_t)(chunk_start + node0 + wid * 16) * 64;
  _Float16* pp1 = pp0 + (size_t)64 * 64;
  int rbase = kg * 4;
#pragma unroll
  for (int j = 0; j < 4; ++j) {
    int row = rbase + j;
    if (node0 + wid * 16 + row < chunk_nodes) {
      pp0[row * 64 + 0  + r16] = (_Float16)p0[j];
      pp0[row * 64 + 16 + r16] = (_Float16)p1[j];
      pp0[row * 64 + 32 + r16] = (_Float16)p2[j];
      pp0[row * 64 + 48 + r16] = (_Float16)p3[j];
    }
    if (node0 + 64 + wid * 16 + row < chunk_nodes) {
      pp1[row * 64 + 0  + r16] = (_Float16)q0[j];
      pp1[row * 64 + 16 + r16] = (_Float16)q1[j];
      pp1[row * 64 + 32 + r16] = (_Float16)q2[j];
      pp1[row * 64 + 48 + r16] = (_Float16)q3[j];
    }
  }
}

// h_new = relu(sum_k part + conv_b); fp16 kpart, fp32 accumulate.
// When do_sum!=0: also emit per-block node-partial sums psum[625][64]
// (fixed-order LDS tree -> deterministic), replacing k_sum_p.
__global__ void __launch_bounds__(256) k_epi(
    const _Float16* __restrict__ part, const float* __restrict__ cb,
    float* __restrict__ hout, float* __restrict__ psum, int do_sum) {
  __shared__ float4 s4[256];
  int t = threadIdx.x;
  int idx4 = blockIdx.x * 256 + t;      // grid covers NN*16 exactly
  int o4 = (idx4 & 15) * 4;
  float4 a = make_float4(cb[o4], cb[o4 + 1], cb[o4 + 2], cb[o4 + 3]);
#pragma unroll
  for (int kc = 0; kc < SPLITK; ++kc) {   // FIXED order: deterministic
    f16x4 pv = *(const f16x4*)&part[(size_t)kc * NN * 64 + (size_t)idx4 * 4];
    a.x += (float)pv[0]; a.y += (float)pv[1];
    a.z += (float)pv[2]; a.w += (float)pv[3];
  }
  float4 r = make_float4(a.x > 0.f ? a.x : 0.f, a.y > 0.f ? a.y : 0.f,
                         a.z > 0.f ? a.z : 0.f, a.w > 0.f ? a.w : 0.f);
  *(float4*)&hout[(size_t)idx4 * 4] = r;
  if (do_sum) {
    // t = node_local*16 + quad; reduce over node_local (stride 16 in t)
    s4[t] = r;
    __syncthreads();
    if (t < 128) { float4 b = s4[t + 128]; s4[t].x += b.x; s4[t].y += b.y; s4[t].z += b.z; s4[t].w += b.w; }
    __syncthreads();
    if (t < 64)  { float4 b = s4[t + 64];  s4[t].x += b.x; s4[t].y += b.y; s4[t].z += b.z; s4[t].w += b.w; }
    __syncthreads();
    if (t < 32)  { float4 b = s4[t + 32];  s4[t].x += b.x; s4[t].y += b.y; s4[t].z += b.z; s4[t].w += b.w; }
    __syncthreads();
    if (t < 16)  {
      float4 b = s4[t + 16];
      float4 v = make_float4(s4[t].x + b.x, s4[t].y + b.y, s4[t].z + b.z, s4[t].w + b.w);
      *(float4*)&psum[(size_t)blockIdx.x * 64 + t * 4] = v;
    }
  }
}

// reduce psum[625][64] -> concat -> bneck (69 -> 384), one block of 384
__global__ void __launch_bounds__(384) k_bneck(
    const float* __restrict__ psum, const float* __restrict__ vpa,
    const float* __restrict__ mz, const float* __restrict__ adduct,
    const float* __restrict__ bw, const float* __restrict__ bb,
    float* __restrict__ aout) {
  __shared__ float in69[69];
  __shared__ float red[256];
  int t = threadIdx.x;
  if (t < 256) {
    int o = t & 63, g = t >> 6;
    float acc = 0.f;
    for (int row = g; row < NEPI; row += 4) acc += psum[(size_t)row * 64 + o];
    red[t] = acc;
  }
  __syncthreads();
  if (t < 64) in69[t] = red[t] + red[64 + t] + red[128 + t] + red[192 + t];
  if (t == 64) in69[64] = vpa[0];
  if (t == 65) in69[65] = mz[0];
  if (t >= 66 && t < 69) in69[t] = adduct[t - 66];
  __syncthreads();
  float acc = bb[t];
#pragma unroll 4
  for (int i = 0; i < 69; ++i) acc += in69[i] * bw[i * 384 + t];
  aout[t] = acc > 0.f ? acc : 0.f;
}

// one 384->384 relu layer, 24 blocks x 256 threads, 16 outputs/block
__global__ void __launch_bounds__(256) k_layer(
    const float* __restrict__ ain, const float* __restrict__ w,
    const float* __restrict__ bias, float* __restrict__ aout) {
  __shared__ float a_s[384];
  __shared__ float red[256];
  int t = threadIdx.x;
  for (int i = t; i < 384; i += 256) a_s[i] = ain[i];
  __syncthreads();
  int o = blockIdx.x * 16 + (t & 15);
  int ig = t >> 4;  // 0..15
  float acc = 0.f;
#pragma unroll
  for (int k = 0; k < 24; ++k) {
    int i = ig + (k << 4);
    acc += a_s[i] * w[i * 384 + o];
  }
  red[t] = acc;
  __syncthreads();
  if (t < 128) red[t] += red[t + 128];
  __syncthreads();
  if (t < 64) red[t] += red[t + 64];
  __syncthreads();
  if (t < 32) red[t] += red[t + 32];
  __syncthreads();
  if (t < 16) {
    float v = red[t] + red[t + 16] + bias[o];
    aout[o] = v > 0.f ? v : 0.f;
  }
}

// final: act @ l2w + l2b -> scalar
__global__ void __launch_bounds__(384) k_out(
    const float* __restrict__ act, const float* __restrict__ l2w,
    const float* __restrict__ l2b, float* __restrict__ out) {
  __shared__ float red[384];
  int t = threadIdx.x;
  red[t] = act[t] * l2w[t];
  __syncthreads();
  if (t < 128) red[t] += red[t + 128] + red[t + 256];
  __syncthreads();
  if (t < 64) {
    float s2 = red[t] + red[t + 64];
#pragma unroll
    for (int off = 32; off; off >>= 1) s2 += __shfl_down(s2, off);
    if (t == 0) out[0] = s2 + l2b[0];
  }
}

extern "C" void kernel_launch(void* const* d_in, const int* in_sizes, int n_in,
                              void* d_out, int out_size, void* d_ws, size_t ws_size,
                              hipStream_t stream) {
  const float* x      = (const float*)d_in[0];
  const int* ei       = (const int*)d_in[1];   // int32 on device
  const float* ea     = (const float*)d_in[2];
  const float* vpa    = (const float*)d_in[3];
  const float* mz     = (const float*)d_in[4];
  const float* adduct = (const float*)d_in[5];
  const float* lin0_w = (const float*)d_in[6];
  const float* lin0_b = (const float*)d_in[7];
  const float* nn1_w  = (const float*)d_in[8];
  const float* nn1_b  = (const float*)d_in[9];
  const float* nn2_w  = (const float*)d_in[10];
  const float* nn2_b  = (const float*)d_in[11];
  const float* root_w = (const float*)d_in[12];
  const float* conv_b = (const float*)d_in[13];
  const float* bw     = (const float*)d_in[14];
  const float* bb     = (const float*)d_in[15];
  const float* l1w    = (const float*)d_in[16];
  const float* l1b    = (const float*)d_in[17];
  const float* l2w    = (const float*)d_in[18];
  const float* l2b    = (const float*)d_in[19];

  char* p = (char*)d_ws;
  auto alloc = [&](size_t bytes) {
    char* r = p;
    p += (bytes + 255) & ~(size_t)255;
    return r;
  };
  float* h0      = (float*)alloc((size_t)NN * 64 * 4);
  float* h1      = (float*)alloc((size_t)NN * 64 * 4);
  float* u       = (float*)alloc((size_t)NE * 64 * 4);
  _Float16* wh   = (_Float16*)alloc((size_t)64 * KTOT * 2);
  _Float16* wl   = (_Float16*)alloc((size_t)64 * KTOT * 2);
  // deg, cursor contiguous -> one memset covers both
  int* deg       = (int*)alloc(NN * 4);
  int* cursor    = (int*)alloc(NN * 4);
  size_t zero_bytes = (size_t)((char*)(cursor + NN) - (char*)deg);
  int* offs      = (int*)alloc((NN + 1) * 4);
  float* invd    = (float*)alloc(NN * 4);
  int* csr_src   = (int*)alloc(NE * 4);
  int* csr_eid   = (int*)alloc(NE * 4);
  float* psum    = (float*)alloc((size_t)NEPI * 64 * 4);
  _Float16* kpart = (_Float16*)alloc((size_t)SPLITK * NN * 64 * 2);
  float* actA    = (float*)alloc(384 * 4);
  float* actB    = (float*)alloc(384 * 4);
  size_t used = (size_t)(p - (char*)d_ws);
  size_t avail = ws_size > used ? ws_size - used : 0;
  long long CH = (long long)(avail / ((size_t)KTOT * 2));  // single fp16 plane
  if (CH > NN) CH = NN;
  if (CH < 1) CH = 1;
  _Float16* sv16 = (_Float16*)p;

  hipMemsetAsync(deg, 0, zero_bytes, stream);

  k_front<<<(NN * 64 + NE * 64 + 255) / 256, 256, 0, stream>>>(
      x, lin0_w, lin0_b, ea, nn1_w, nn1_b, ei, h0, u, deg);
  k_scan<<<1, 256, 0, stream>>>(deg, offs, invd);
  k_csr<<<(NE + 255) / 256, 256, 0, stream>>>(ei, offs, cursor, csr_src, csr_eid);
  k_wf<<<(64 * KTOT + 255) / 256, 256, 0, stream>>>(nn2_w, nn2_b, root_w, wh, wl);

  float* hc = h0;
  float* hn = h1;
  for (int it = 0; it < 3; ++it) {
    for (int cs = 0; cs < NN; cs += (int)CH) {
      int cn = (NN - cs < (int)CH) ? (NN - cs) : (int)CH;
      k_scatter<<<(cn + 1) / 2, 128, 0, stream>>>(hc, u, offs, csr_src, csr_eid,
                                                  invd, sv16, cs, cn);
      dim3 g2((cn + 127) / 128, SPLITK);
      k_mfma<<<g2, 256, 0, stream>>>(sv16, wh, wl, kpart, cs, cn);
    }
    k_epi<<<NEPI, 256, 0, stream>>>(kpart, conv_b, hn, psum, (it == 2) ? 1 : 0);
    float* tmp = hc; hc = hn; hn = tmp;
  }
  k_bneck<<<1, 384, 0, stream>>>(psum, vpa, mz, adduct, bw, bb, actA);
  float* ain = actA;
  float* aout = actB;
  for (int L = 0; L < 6; ++L) {
    k_layer<<<24, 256, 0, stream>>>(ain, l1w, l1b, aout);
    float* tmp = ain; ain = aout; aout = tmp;
  }
  k_out<<<1, 384, 0, stream>>>(ain, l2w, l2b, (float*)d_out);
}

// Round 18
// 282.158 us; speedup vs baseline: 1.1019x; 1.1019x over previous
//
#include <hip/hip_runtime.h>
#include <stdint.h>

#define NN 10000
#define NE 50000
#define KTOT 4224   // 4096 (S) + 64 (hs/bias) + 64 (h/root)
#define SPLITK 11
#define KCH 384     // KTOT / SPLITK = 12 k-steps of 32 (3 LDS stages of 128)
#define NSTEP 12
#define KPAD2 136   // LDS row stride (halves) for a 128-col stage (272 B)

typedef __attribute__((ext_vector_type(8))) _Float16 f16x8;
typedef __attribute__((ext_vector_type(4))) _Float16 f16x4;
typedef __attribute__((ext_vector_type(4))) float f32x4;

// fused: h = relu(x@lin0_w+b), u = relu(ea@nn1_w+b), deg[dst] histogram
__global__ void k_front(const float* __restrict__ x, const float* __restrict__ l0w,
                        const float* __restrict__ l0b, const float* __restrict__ ea,
                        const float* __restrict__ n1w, const float* __restrict__ n1b,
                        const int* __restrict__ ei, float* __restrict__ h,
                        float* __restrict__ u, int* __restrict__ deg) {
  int idx = blockIdx.x * blockDim.x + threadIdx.x;
  if (idx < NN * 64) {
    int n = idx >> 6, o = idx & 63;
    float acc = l0b[o];
    const float* xr = x + n * 20;
#pragma unroll
    for (int j = 0; j < 20; ++j) acc += xr[j] * l0w[j * 64 + o];
    h[idx] = acc > 0.f ? acc : 0.f;
  } else {
    int idx2 = idx - NN * 64;
    if (idx2 >= NE * 64) return;
    int e = idx2 >> 6, o = idx2 & 63;
    if (o == 0) atomicAdd(&deg[ei[NE + e]], 1);   // fused k_deg
    float acc = n1b[o];
    const float* er = ea + e * 5;
#pragma unroll
    for (int j = 0; j < 5; ++j) acc += er[j] * n1w[j * 64 + o];
    u[idx2] = acc > 0.f ? acc : 0.f;
  }
}

// exclusive scan of deg -> offs[0..NN], plus inv_denom = 1/max(deg,1)
__global__ void k_scan(const int* __restrict__ deg, int* __restrict__ offs,
                       float* __restrict__ inv_denom) {
  __shared__ int s[256];
  int t = threadIdx.x;
  int base = t * 40;
  int sum = 0;
  for (int j = 0; j < 40; ++j) {
    int n = base + j;
    sum += (n < NN) ? deg[n] : 0;
  }
  s[t] = sum;
  __syncthreads();
  for (int off = 1; off < 256; off <<= 1) {
    int v = (t >= off) ? s[t - off] : 0;
    __syncthreads();
    s[t] += v;
    __syncthreads();
  }
  int run = s[t] - sum;  // exclusive prefix for this thread's chunk
  for (int j = 0; j < 40; ++j) {
    int n = base + j;
    if (n < NN) {
      offs[n] = run;
      int d = deg[n];
      run += d;
      inv_denom[n] = 1.0f / (float)(d > 0 ? d : 1);
    }
  }
  if (t == 255) offs[NN] = s[255];
}

__global__ void k_csr(const int* __restrict__ ei, const int* __restrict__ offs,
                      int* __restrict__ cursor, int* __restrict__ csr_src,
                      int* __restrict__ csr_eid) {
  int e = blockIdx.x * blockDim.x + threadIdx.x;
  if (e >= NE) return;
  int d = ei[NE + e];
  int pos = offs[d] + atomicAdd(&cursor[d], 1);
  csr_src[pos] = ei[e];
  csr_eid[pos] = e;
}

// WF transposed [o][k] as fp16 hi/lo planes (W fp32-grade), o=0..63.
__global__ void k_wf(const float* __restrict__ w2, const float* __restrict__ b2,
                     const float* __restrict__ rootw, _Float16* __restrict__ wh,
                     _Float16* __restrict__ wl) {
  int idx = blockIdx.x * blockDim.x + threadIdx.x;
  if (idx >= 64 * KTOT) return;
  int o = idx / KTOT, c = idx - o * KTOT;
  float v;
  if (c < 4096) {
    v = w2[(c >> 6) * 4096 + (c & 63) * 64 + o];
  } else if (c < 4160) {
    v = b2[(c - 4096) * 64 + o];
  } else {
    v = rootw[(c - 4160) * 64 + o];
  }
  _Float16 hi = (_Float16)v;
  wh[idx] = hi;
  wl[idx] = (_Float16)(v - (float)hi);
}

// Per node: SV row = [ inv_d*S(k,i) (4096) | inv_d*hs (64) | h[n] (64) ] (fp16)
// One WAVE per node (2 nodes/block, 128 thr), lane = k. Edge QUADS per
// iteration; invalid slots masked by uk=0 (order-stable numerics).
__global__ void __launch_bounds__(128) k_scatter(
    const float* __restrict__ h, const float* __restrict__ u,
    const int* __restrict__ offs, const int* __restrict__ csr_src,
    const int* __restrict__ csr_eid, const float* __restrict__ inv_denom,
    _Float16* __restrict__ sv16, int chunk_start, int chunk_nodes) {
  __shared__ float hrow[2][4][64];
  int t = threadIdx.x;
  int wid = t >> 6, lane = t & 63;
  int n_local = blockIdx.x * 2 + wid;
  if (n_local >= chunk_nodes) return;
  int n = chunk_start + n_local;
  int beg = offs[n], end = offs[n + 1];
  int nE = end - beg;
  float invd = inv_denom[n];
  float acc[64];
#pragma unroll
  for (int i = 0; i < 64; ++i) acc[i] = 0.f;
  float hsacc = 0.f;
  float uc0 = 0.f, uc1 = 0.f, uc2 = 0.f, uc3 = 0.f;
  float hc0 = 0.f, hc1 = 0.f, hc2 = 0.f, hc3 = 0.f;
  if (0 < nE) { int e = csr_eid[beg + 0], s = csr_src[beg + 0];
    uc0 = u[(size_t)e * 64 + lane]; hc0 = h[(size_t)s * 64 + lane]; }
  if (1 < nE) { int e = csr_eid[beg + 1], s = csr_src[beg + 1];
    uc1 = u[(size_t)e * 64 + lane]; hc1 = h[(size_t)s * 64 + lane]; }
  if (2 < nE) { int e = csr_eid[beg + 2], s = csr_src[beg + 2];
    uc2 = u[(size_t)e * 64 + lane]; hc2 = h[(size_t)s * 64 + lane]; }
  if (3 < nE) { int e = csr_eid[beg + 3], s = csr_src[beg + 3];
    uc3 = u[(size_t)e * 64 + lane]; hc3 = h[(size_t)s * 64 + lane]; }
  for (int c = 0; c < nE; c += 4) {
    hrow[wid][0][lane] = hc0;
    hrow[wid][1][lane] = hc1;
    hrow[wid][2][lane] = hc2;
    hrow[wid][3][lane] = hc3;
    hsacc += hc0 + hc1 + hc2 + hc3;    // invalid slots are 0
    float uk0 = uc0, uk1 = uc1, uk2 = uc2, uk3 = uc3;
    // prefetch next quad (issue before FMA burst)
    uc0 = uc1 = uc2 = uc3 = 0.f;
    hc0 = hc1 = hc2 = hc3 = 0.f;
    if (c + 4 < nE) { int e = csr_eid[beg + c + 4], s = csr_src[beg + c + 4];
      uc0 = u[(size_t)e * 64 + lane]; hc0 = h[(size_t)s * 64 + lane]; }
    if (c + 5 < nE) { int e = csr_eid[beg + c + 5], s = csr_src[beg + c + 5];
      uc1 = u[(size_t)e * 64 + lane]; hc1 = h[(size_t)s * 64 + lane]; }
    if (c + 6 < nE) { int e = csr_eid[beg + c + 6], s = csr_src[beg + c + 6];
      uc2 = u[(size_t)e * 64 + lane]; hc2 = h[(size_t)s * 64 + lane]; }
    if (c + 7 < nE) { int e = csr_eid[beg + c + 7], s = csr_src[beg + c + 7];
      uc3 = u[(size_t)e * 64 + lane]; hc3 = h[(size_t)s * 64 + lane]; }
#pragma unroll
    for (int j = 0; j < 16; ++j) {
      float4 r0 = *(const float4*)&hrow[wid][0][j * 4];
      float4 r1 = *(const float4*)&hrow[wid][1][j * 4];
      float4 r2 = *(const float4*)&hrow[wid][2][j * 4];
      float4 r3 = *(const float4*)&hrow[wid][3][j * 4];
      acc[j * 4 + 0] += uk0 * r0.x + uk1 * r1.x + uk2 * r2.x + uk3 * r3.x;
      acc[j * 4 + 1] += uk0 * r0.y + uk1 * r1.y + uk2 * r2.y + uk3 * r3.y;
      acc[j * 4 + 2] += uk0 * r0.z + uk1 * r1.z + uk2 * r2.z + uk3 * r3.z;
      acc[j * 4 + 3] += uk0 * r0.w + uk1 * r1.w + uk2 * r2.w + uk3 * r3.w;
    }
  }
  size_t rowo = (size_t)n_local * KTOT + (size_t)lane * 64;
#pragma unroll
  for (int j = 0; j < 8; ++j) {
    f16x8 v;
#pragma unroll
    for (int q = 0; q < 8; ++q) v[q] = (_Float16)(acc[j * 8 + q] * invd);
    *(f16x8*)(sv16 + rowo + j * 8) = v;
  }
  size_t base = (size_t)n_local * KTOT;
  sv16[base + 4096 + lane] = (_Float16)(hsacc * invd);
  sv16[base + 4160 + lane] = (_Float16)(h[(size_t)n * 64 + lane]);
}

// Split-K MFMA GEMM, fp16 2-pass, B in LDS (3 stages of 128), 2-stripe.
// K-steps processed in PAIRS with 2-deep A register prefetch. kpart fp16.
__global__ void __launch_bounds__(256) k_mfma(
    const _Float16* __restrict__ sv16, const _Float16* __restrict__ wh,
    const _Float16* __restrict__ wl, _Float16* __restrict__ part,
    int chunk_start, int chunk_nodes) {
  __shared__ _Float16 Bh_s[64 * KPAD2];
  __shared__ _Float16 Bl_s[64 * KPAD2];
  int t = threadIdx.x;
  int wid = t >> 6, lane = t & 63;
  int node0 = blockIdx.x * 128;
  int kc = blockIdx.y;
  int r16 = lane & 15, kg = lane >> 4;
  int row0 = node0 + wid * 16 + r16;         // stripe 0
  int row1 = row0 + 64;                      // stripe 1
  int rg0 = row0 < chunk_nodes ? row0 : (chunk_nodes - 1);
  int rg1 = row1 < chunk_nodes ? row1 : (chunk_nodes - 1);
  const _Float16* pa0 = sv16 + (size_t)rg0 * KTOT + kg * 8;
  const _Float16* pa1 = sv16 + (size_t)rg1 * KTOT + kg * 8;
  f32x4 p0 = {0.f, 0.f, 0.f, 0.f}, p1 = p0, p2 = p0, p3 = p0;   // stripe 0
  f32x4 q0 = p0, q1 = p0, q2 = p0, q3 = p0;                      // stripe 1
  const int kb0 = kc * KCH;
  // 2-deep prefetch: c* = step ks, d* = step ks+1
  f16x8 c0 = *(const f16x8*)(pa0 + kb0);
  f16x8 c1 = *(const f16x8*)(pa1 + kb0);
  f16x8 d0 = *(const f16x8*)(pa0 + kb0 + 32);
  f16x8 d1 = *(const f16x8*)(pa1 + kb0 + 32);
  const int lb = r16 * KPAD2 + kg * 8;   // lane's LDS base (o-row r16)
#pragma unroll 1
  for (int ks = 0; ks < NSTEP; ks += 2) {
    if ((ks & 3) == 0) {                // (re)stage B: 128 cols, both planes
      __syncthreads();                  // prior stage fully consumed
      int gb = kb0 + (ks >> 2) * 128;
#pragma unroll
      for (int j = 0; j < 4; ++j) {
        int c = j * 256 + t;            // 0..1023
        int o = c >> 4, kk = (c & 15) * 8;
        *(f16x8*)&Bh_s[o * KPAD2 + kk] = *(const f16x8*)&wh[(size_t)o * KTOT + gb + kk];
        *(f16x8*)&Bl_s[o * KPAD2 + kk] = *(const f16x8*)&wl[(size_t)o * KTOT + gb + kk];
      }
      __syncthreads();
    }
    // prefetch steps ks+2, ks+3 (clamped)
    int kp2 = kb0 + ((ks + 2 < NSTEP) ? (ks + 2) : (NSTEP - 1)) * 32;
    int kp3 = kb0 + ((ks + 3 < NSTEP) ? (ks + 3) : (NSTEP - 1)) * 32;
    f16x8 e0 = *(const f16x8*)(pa0 + kp2);
    f16x8 e1 = *(const f16x8*)(pa1 + kp2);
    f16x8 f0 = *(const f16x8*)(pa0 + kp3);
    f16x8 f1 = *(const f16x8*)(pa1 + kp3);
    // ---- step ks (A = c0,c1) ----
    {
      int lk = lb + (ks & 3) * 32;
      f16x8 bh0 = *(const f16x8*)&Bh_s[lk];
      f16x8 bh1 = *(const f16x8*)&Bh_s[lk + 16 * KPAD2];
      f16x8 bh2 = *(const f16x8*)&Bh_s[lk + 32 * KPAD2];
      f16x8 bh3 = *(const f16x8*)&Bh_s[lk + 48 * KPAD2];
      f16x8 bl0 = *(const f16x8*)&Bl_s[lk];
      f16x8 bl1 = *(const f16x8*)&Bl_s[lk + 16 * KPAD2];
      f16x8 bl2 = *(const f16x8*)&Bl_s[lk + 32 * KPAD2];
      f16x8 bl3 = *(const f16x8*)&Bl_s[lk + 48 * KPAD2];
      p0 = __builtin_amdgcn_mfma_f32_16x16x32_f16(c0, bh0, p0, 0, 0, 0);
      p1 = __builtin_amdgcn_mfma_f32_16x16x32_f16(c0, bh1, p1, 0, 0, 0);
      p2 = __builtin_amdgcn_mfma_f32_16x16x32_f16(c0, bh2, p2, 0, 0, 0);
      p3 = __builtin_amdgcn_mfma_f32_16x16x32_f16(c0, bh3, p3, 0, 0, 0);
      p0 = __builtin_amdgcn_mfma_f32_16x16x32_f16(c0, bl0, p0, 0, 0, 0);
      p1 = __builtin_amdgcn_mfma_f32_16x16x32_f16(c0, bl1, p1, 0, 0, 0);
      p2 = __builtin_amdgcn_mfma_f32_16x16x32_f16(c0, bl2, p2, 0, 0, 0);
      p3 = __builtin_amdgcn_mfma_f32_16x16x32_f16(c0, bl3, p3, 0, 0, 0);
      q0 = __builtin_amdgcn_mfma_f32_16x16x32_f16(c1, bh0, q0, 0, 0, 0);
      q1 = __builtin_amdgcn_mfma_f32_16x16x32_f16(c1, bh1, q1, 0, 0, 0);
      q2 = __builtin_amdgcn_mfma_f32_16x16x32_f16(c1, bh2, q2, 0, 0, 0);
      q3 = __builtin_amdgcn_mfma_f32_16x16x32_f16(c1, bh3, q3, 0, 0, 0);
      q0 = __builtin_amdgcn_mfma_f32_16x16x32_f16(c1, bl0, q0, 0, 0, 0);
      q1 = __builtin_amdgcn_mfma_f32_16x16x32_f16(c1, bl1, q1, 0, 0, 0);
      q2 = __builtin_amdgcn_mfma_f32_16x16x32_f16(c1, bl2, q2, 0, 0, 0);
      q3 = __builtin_amdgcn_mfma_f32_16x16x32_f16(c1, bl3, q3, 0, 0, 0);
    }
    // ---- step ks+1 (A = d0,d1) ----
    {
      int lk = lb + ((ks + 1) & 3) * 32;
      f16x8 bh0 = *(const f16x8*)&Bh_s[lk];
      f16x8 bh1 = *(const f16x8*)&Bh_s[lk + 16 * KPAD2];
      f16x8 bh2 = *(const f16x8*)&Bh_s[lk + 32 * KPAD2];
      f16x8 bh3 = *(const f16x8*)&Bh_s[lk + 48 * KPAD2];
      f16x8 bl0 = *(const f16x8*)&Bl_s[lk];
      f16x8 bl1 = *(const f16x8*)&Bl_s[lk + 16 * KPAD2];
      f16x8 bl2 = *(const f16x8*)&Bl_s[lk + 32 * KPAD2];
      f16x8 bl3 = *(const f16x8*)&Bl_s[lk + 48 * KPAD2];
      p0 = __builtin_amdgcn_mfma_f32_16x16x32_f16(d0, bh0, p0, 0, 0, 0);
      p1 = __builtin_amdgcn_mfma_f32_16x16x32_f16(d0, bh1, p1, 0, 0, 0);
      p2 = __builtin_amdgcn_mfma_f32_16x16x32_f16(d0, bh2, p2, 0, 0, 0);
      p3 = __builtin_amdgcn_mfma_f32_16x16x32_f16(d0, bh3, p3, 0, 0, 0);
      p0 = __builtin_amdgcn_mfma_f32_16x16x32_f16(d0, bl0, p0, 0, 0, 0);
      p1 = __builtin_amdgcn_mfma_f32_16x16x32_f16(d0, bl1, p1, 0, 0, 0);
      p2 = __builtin_amdgcn_mfma_f32_16x16x32_f16(d0, bl2, p2, 0, 0, 0);
      p3 = __builtin_amdgcn_mfma_f32_16x16x32_f16(d0, bl3, p3, 0, 0, 0);
      q0 = __builtin_amdgcn_mfma_f32_16x16x32_f16(d1, bh0, q0, 0, 0, 0);
      q1 = __builtin_amdgcn_mfma_f32_16x16x32_f16(d1, bh1, q1, 0, 0, 0);
      q2 = __builtin_amdgcn_mfma_f32_16x16x32_f16(d1, bh2, q2, 0, 0, 0);
      q3 = __builtin_amdgcn_mfma_f32_16x16x32_f16(d1, bh3, q3, 0, 0, 0);
      q0 = __builtin_amdgcn_mfma_f32_16x16x32_f16(d1, bl0, q0, 0, 0, 0);
      q1 = __builtin_amdgcn_mfma_f32_16x16x32_f16(d1, bl1, q1, 0, 0, 0);
      q2 = __builtin_amdgcn_mfma_f32_16x16x32_f16(d1, bl2, q2, 0, 0, 0);
      q3 = __builtin_amdgcn_mfma_f32_16x16x32_f16(d1, bl3, q3, 0, 0, 0);
    }
    c0 = e0; c1 = e1; d0 = f0; d1 = f1;
  }
  // C/D layout: col = lane&15, row = (lane>>4)*4 + reg  [m89]
  _Float16* pp0 = part + (size_t)kc * NN * 64 +
                  (size_t)(chunk_start + node0 + wid * 16) * 64;
  _Float16* pp1 = pp0 + (size_t)64 * 64;
  int rbase = kg * 4;
#pragma unroll
  for (int j = 0; j < 4; ++j) {
    int row = rbase + j;
    if (node0 + wid * 16 + row < chunk_nodes) {
      pp0[row * 64 + 0  + r16] = (_Float16)p0[j];
      pp0[row * 64 + 16 + r16] = (_Float16)p1[j];
      pp0[row * 64 + 32 + r16] = (_Float16)p2[j];
      pp0[row * 64 + 48 + r16] = (_Float16)p3[j];
    }
    if (node0 + 64 + wid * 16 + row < chunk_nodes) {
      pp1[row * 64 + 0  + r16] = (_Float16)q0[j];
      pp1[row * 64 + 16 + r16] = (_Float16)q1[j];
      pp1[row * 64 + 32 + r16] = (_Float16)q2[j];
      pp1[row * 64 + 48 + r16] = (_Float16)q3[j];
    }
  }
}

// h_new = relu(sum_k part + conv_b)   — fp16 kpart, fp32 accumulate
__global__ void k_epi(const _Float16* __restrict__ part, const float* __restrict__ cb,
                      float* __restrict__ hout) {
  int idx4 = blockIdx.x * blockDim.x + threadIdx.x;
  if (idx4 >= NN * 16) return;
  int o4 = (idx4 & 15) * 4;
  float4 a = make_float4(cb[o4], cb[o4 + 1], cb[o4 + 2], cb[o4 + 3]);
#pragma unroll
  for (int kc = 0; kc < SPLITK; ++kc) {   // FIXED order: deterministic
    f16x4 pv = *(const f16x4*)&part[(size_t)kc * NN * 64 + (size_t)idx4 * 4];
    a.x += (float)pv[0]; a.y += (float)pv[1];
    a.z += (float)pv[2]; a.w += (float)pv[3];
  }
  float4 r = make_float4(a.x > 0.f ? a.x : 0.f, a.y > 0.f ? a.y : 0.f,
                         a.z > 0.f ? a.z : 0.f, a.w > 0.f ? a.w : 0.f);
  *(float4*)&hout[(size_t)idx4 * 4] = r;
}

// partial node-sum: part[160][64]
__global__ void k_sum_p(const float* __restrict__ h, float* __restrict__ part) {
  __shared__ float s[256];
  int t = threadIdx.x, b = blockIdx.x;
  int o = t & 63, g = t >> 6;
  float acc = 0.f;
  for (int k = 0;; ++k) {
    int n = b + 160 * (g + 4 * k);
    if (n >= NN) break;
    acc += h[(size_t)n * 64 + o];
  }
  s[t] = acc;
  __syncthreads();
  if (t < 64) part[(size_t)b * 64 + t] = s[t] + s[64 + t] + s[128 + t] + s[192 + t];
}

// reduce partials -> concat -> bneck (69 -> 384), one block of 384
__global__ void __launch_bounds__(384) k_bneck(
    const float* __restrict__ part, const float* __restrict__ vpa,
    const float* __restrict__ mz, const float* __restrict__ adduct,
    const float* __restrict__ bw, const float* __restrict__ bb,
    float* __restrict__ aout) {
  __shared__ float in69[69];
  __shared__ float red[256];
  int t = threadIdx.x;
  if (t < 256) {
    int o = t & 63, g = t >> 6;
    float acc = 0.f;
    for (int k = 0; k < 40; ++k) acc += part[(size_t)(g * 40 + k) * 64 + o];
    red[t] = acc;
  }
  __syncthreads();
  if (t < 64) in69[t] = red[t] + red[64 + t] + red[128 + t] + red[192 + t];
  if (t == 64) in69[64] = vpa[0];
  if (t == 65) in69[65] = mz[0];
  if (t >= 66 && t < 69) in69[t] = adduct[t - 66];
  __syncthreads();
  float acc = bb[t];
#pragma unroll 4
  for (int i = 0; i < 69; ++i) acc += in69[i] * bw[i * 384 + t];
  aout[t] = acc > 0.f ? acc : 0.f;
}

// one 384->384 relu layer, 24 blocks x 256 threads, 16 outputs/block
__global__ void __launch_bounds__(256) k_layer(
    const float* __restrict__ ain, const float* __restrict__ w,
    const float* __restrict__ bias, float* __restrict__ aout) {
  __shared__ float a_s[384];
  __shared__ float red[256];
  int t = threadIdx.x;
  for (int i = t; i < 384; i += 256) a_s[i] = ain[i];
  __syncthreads();
  int o = blockIdx.x * 16 + (t & 15);
  int ig = t >> 4;  // 0..15
  float acc = 0.f;
#pragma unroll
  for (int k = 0; k < 24; ++k) {
    int i = ig + (k << 4);
    acc += a_s[i] * w[i * 384 + o];
  }
  red[t] = acc;
  __syncthreads();
  if (t < 128) red[t] += red[t + 128];
  __syncthreads();
  if (t < 64) red[t] += red[t + 64];
  __syncthreads();
  if (t < 32) red[t] += red[t + 32];
  __syncthreads();
  if (t < 16) {
    float v = red[t] + red[t + 16] + bias[o];
    aout[o] = v > 0.f ? v : 0.f;
  }
}

// final: act @ l2w + l2b -> scalar
__global__ void __launch_bounds__(384) k_out(
    const float* __restrict__ act, const float* __restrict__ l2w,
    const float* __restrict__ l2b, float* __restrict__ out) {
  __shared__ float red[384];
  int t = threadIdx.x;
  red[t] = act[t] * l2w[t];
  __syncthreads();
  if (t < 128) red[t] += red[t + 128] + red[t + 256];
  __syncthreads();
  if (t < 64) {
    float s2 = red[t] + red[t + 64];
#pragma unroll
    for (int off = 32; off; off >>= 1) s2 += __shfl_down(s2, off);
    if (t == 0) out[0] = s2 + l2b[0];
  }
}

extern "C" void kernel_launch(void* const* d_in, const int* in_sizes, int n_in,
                              void* d_out, int out_size, void* d_ws, size_t ws_size,
                              hipStream_t stream) {
  const float* x      = (const float*)d_in[0];
  const int* ei       = (const int*)d_in[1];   // int32 on device
  const float* ea     = (const float*)d_in[2];
  const float* vpa    = (const float*)d_in[3];
  const float* mz     = (const float*)d_in[4];
  const float* adduct = (const float*)d_in[5];
  const float* lin0_w = (const float*)d_in[6];
  const float* lin0_b = (const float*)d_in[7];
  const float* nn1_w  = (const float*)d_in[8];
  const float* nn1_b  = (const float*)d_in[9];
  const float* nn2_w  = (const float*)d_in[10];
  const float* nn2_b  = (const float*)d_in[11];
  const float* root_w = (const float*)d_in[12];
  const float* conv_b = (const float*)d_in[13];
  const float* bw     = (const float*)d_in[14];
  const float* bb     = (const float*)d_in[15];
  const float* l1w    = (const float*)d_in[16];
  const float* l1b    = (const float*)d_in[17];
  const float* l2w    = (const float*)d_in[18];
  const float* l2b    = (const float*)d_in[19];

  char* p = (char*)d_ws;
  auto alloc = [&](size_t bytes) {
    char* r = p;
    p += (bytes + 255) & ~(size_t)255;
    return r;
  };
  float* h0      = (float*)alloc((size_t)NN * 64 * 4);
  float* h1      = (float*)alloc((size_t)NN * 64 * 4);
  float* u       = (float*)alloc((size_t)NE * 64 * 4);
  _Float16* wh   = (_Float16*)alloc((size_t)64 * KTOT * 2);
  _Float16* wl   = (_Float16*)alloc((size_t)64 * KTOT * 2);
  // deg, cursor contiguous -> one memset covers both
  int* deg       = (int*)alloc(NN * 4);
  int* cursor    = (int*)alloc(NN * 4);
  size_t zero_bytes = (size_t)((char*)(cursor + NN) - (char*)deg);
  int* offs      = (int*)alloc((NN + 1) * 4);
  float* invd    = (float*)alloc(NN * 4);
  int* csr_src   = (int*)alloc(NE * 4);
  int* csr_eid   = (int*)alloc(NE * 4);
  float* part    = (float*)alloc(160 * 64 * 4);
  _Float16* kpart = (_Float16*)alloc((size_t)SPLITK * NN * 64 * 2);
  float* actA    = (float*)alloc(384 * 4);
  float* actB    = (float*)alloc(384 * 4);
  size_t used = (size_t)(p - (char*)d_ws);
  size_t avail = ws_size > used ? ws_size - used : 0;
  long long CH = (long long)(avail / ((size_t)KTOT * 2));  // single fp16 plane
  if (CH > NN) CH = NN;
  if (CH < 1) CH = 1;
  _Float16* sv16 = (_Float16*)p;

  hipMemsetAsync(deg, 0, zero_bytes, stream);

  k_front<<<(NN * 64 + NE * 64 + 255) / 256, 256, 0, stream>>>(
      x, lin0_w, lin0_b, ea, nn1_w, nn1_b, ei, h0, u, deg);
  k_scan<<<1, 256, 0, stream>>>(deg, offs, invd);
  k_csr<<<(NE + 255) / 256, 256, 0, stream>>>(ei, offs, cursor, csr_src, csr_eid);
  k_wf<<<(64 * KTOT + 255) / 256, 256, 0, stream>>>(nn2_w, nn2_b, root_w, wh, wl);

  float* hc = h0;
  float* hn = h1;
  for (int it = 0; it < 3; ++it) {
    for (int cs = 0; cs < NN; cs += (int)CH) {
      int cn = (NN - cs < (int)CH) ? (NN - cs) : (int)CH;
      k_scatter<<<(cn + 1) / 2, 128, 0, stream>>>(hc, u, offs, csr_src, csr_eid,
                                                  invd, sv16, cs, cn);
      dim3 g2((cn + 127) / 128, SPLITK);
      k_mfma<<<g2, 256, 0, stream>>>(sv16, wh, wl, kpart, cs, cn);
    }
    k_epi<<<(NN * 16 + 255) / 256, 256, 0, stream>>>(kpart, conv_b, hn);
    float* tmp = hc; hc = hn; hn = tmp;
  }
  k_sum_p<<<160, 256, 0, stream>>>(hc, part);
  k_bneck<<<1, 384, 0, stream>>>(part, vpa, mz, adduct, bw, bb, actA);
  float* ain = actA;
  float* aout = actB;
  for (int L = 0; L < 6; ++L) {
    k_layer<<<24, 256, 0, stream>>>(ain, l1w, l1b, aout);
    float* tmp = ain; ain = aout; aout = tmp;
  }
  k_out<<<1, 384, 0, stream>>>(ain, l2w, l2b, (float*)d_out);
}